// Round 4
// baseline (271.371 us; speedup 1.0000x reference)
//
#include <hip/hip_runtime.h>
#include <hip/hip_bf16.h>

typedef __attribute__((ext_vector_type(4))) float          f32x4;
typedef __attribute__((ext_vector_type(8))) short          bf16x8;
typedef __attribute__((ext_vector_type(8))) unsigned short u16x8;

#define Cc 512
#define Vv 512
#define BM 64
#define KH 256          // K half
#define NTILE 2500
#define GRID 250        // 250 blocks x 10 tiles

// Pre-swizzled bf16 W (MFMA B-fragment order) + f32 tanh of enc/pred rows.
__device__ unsigned short g_W2[Vv * Cc];
__device__ float g_ta[1600 * Cc];
__device__ float g_tp[400 * Cc];

__device__ __forceinline__ unsigned short f2bf(float f) {
    unsigned u = __float_as_uint(f);
    unsigned r = 0x7FFFu + ((u >> 16) & 1u);
    return (unsigned short)((u + r) >> 16);
}

__device__ __forceinline__ float fast_tanh(float x) {
    float e = __expf(2.0f * x);
    return 1.0f - 2.0f * __builtin_amdgcn_rcpf(e + 1.0f);
}

// blocks [0,128) -> W2 swizzle; [128,528) -> tanh(enc); [528,628) -> tanh(pred)
__global__ __launch_bounds__(256) void prep_kernel(
    const float* __restrict__ W, const float* __restrict__ enc,
    const float* __restrict__ pred)
{
    const int b = blockIdx.x;
    if (b < 128) {
        int gid = b * 256 + threadIdx.x;
        int v = gid >> 6;
        int k = (gid & 63) * 8;
        f32x4 a = *(const f32x4*)(W + v * Cc + k);
        f32x4 c = *(const f32x4*)(W + v * Cc + k + 4);
        u16x8 o;
#pragma unroll
        for (int j = 0; j < 4; ++j) {
            o[j]     = f2bf(a[j]);
            o[4 + j] = f2bf(c[j]);
        }
        int frag = (v >> 4) * 16 + (k >> 5);
        int lane = (v & 15) + 16 * ((k >> 3) & 3);
        *(u16x8*)(&g_W2[frag * 512 + lane * 8]) = o;
    } else if (b < 528) {
        int gid = (b - 128) * 256 + threadIdx.x;
        f32x4 a = *(const f32x4*)(enc + gid * 8);
        f32x4 c = *(const f32x4*)(enc + gid * 8 + 4);
        f32x4 o0, o1;
#pragma unroll
        for (int j = 0; j < 4; ++j) { o0[j] = fast_tanh(a[j]); o1[j] = fast_tanh(c[j]); }
        *(f32x4*)(g_ta + gid * 8)     = o0;
        *(f32x4*)(g_ta + gid * 8 + 4) = o1;
    } else {
        int gid = (b - 528) * 256 + threadIdx.x;
        f32x4 a = *(const f32x4*)(pred + gid * 8);
        f32x4 c = *(const f32x4*)(pred + gid * 8 + 4);
        f32x4 o0, o1;
#pragma unroll
        for (int j = 0; j < 4; ++j) { o0[j] = fast_tanh(a[j]); o1[j] = fast_tanh(c[j]); }
        *(f32x4*)(g_tp + gid * 8)     = o0;
        *(f32x4*)(g_tp + gid * 8 + 4) = o1;
    }
}

__global__ __launch_bounds__(512, 2) void joiner_main(
    const float* __restrict__ bias,  // (512,)
    float* __restrict__ out)         // (160000, 512)
{
    __shared__ unsigned short As[2][BM * KH];   // 2 x 32KB half-K buffers

    const int tid  = threadIdx.x;
    const int lane = tid & 63;
    const int w    = tid >> 6;          // wave -> V slice [w*64, w*64+64)
    const int lc   = lane & 15;
    const int lkB  = (lane >> 4) << 4;  // k byte-offset within 32-elem step
    const int lr   = (lane >> 4) << 2;

    // stage mapping: row sr (0..63), chunk slot sq (0..7), 4 chunks of 8 elems
    const int sr = tid >> 3;
    const int sq = tid & 7;
    const int swzS = (sr & 7) << 4;

    const unsigned short* wb = &g_W2[0];

    float bia[4];
#pragma unroll
    for (int j = 0; j < 4; ++j) bia[j] = bias[w * 64 + j * 16 + lc];

    f32x4 eR[8], pR[8];                 // staged next-half inputs (64 VGPR)

    auto issueLoads = [&](int t, int h) {
        int m  = t * BM + sr;
        int et = m / 100;
        int u  = m - et * 100;
        int bb = m / 40000;
        int pr = bb * 100 + u;
        const float* taP = g_ta + et * Cc + h * KH + sq * 8;
        const float* tpP = g_tp + pr * Cc + h * KH + sq * 8;
#pragma unroll
        for (int c = 0; c < 4; ++c) {
            eR[2 * c]     = *(const f32x4*)(taP + c * 64);
            eR[2 * c + 1] = *(const f32x4*)(taP + c * 64 + 4);
            pR[2 * c]     = *(const f32x4*)(tpP + c * 64);
            pR[2 * c + 1] = *(const f32x4*)(tpP + c * 64 + 4);
        }
    };

    auto convertWrite = [&](int buf) {
        char* base = (char*)(&As[buf][0]);
#pragma unroll
        for (int c = 0; c < 4; ++c) {
            u16x8 o;
#pragma unroll
            for (int j = 0; j < 4; ++j) {
                float a0 = eR[2 * c][j],     p0 = pR[2 * c][j];
                float a1 = eR[2 * c + 1][j], p1 = pR[2 * c + 1][j];
                float n0 = a0 + p0, d0 = __builtin_fmaf(a0, p0, 1.0f);
                o[j]     = f2bf(n0 * __builtin_amdgcn_rcpf(d0));
                float n1 = a1 + p1, d1 = __builtin_fmaf(a1, p1, 1.0f);
                o[4 + j] = f2bf(n1 * __builtin_amdgcn_rcpf(d1));
            }
            int byte = sr * 512 + sq * 16 + c * 128;
            *(u16x8*)(base + (byte ^ swzS)) = o;
        }
    };

    f32x4 acc[4][4];
#pragma unroll
    for (int i = 0; i < 4; ++i)
#pragma unroll
        for (int j = 0; j < 4; ++j)
            acc[i][j] = (f32x4){0.f, 0.f, 0.f, 0.f};

    bf16x8 bfr[2][4];   // 2-deep B-fragment ring
    auto loadB = [&](int slot, int ks) {
#pragma unroll
        for (int j = 0; j < 4; ++j)
            bfr[slot][j] = *(const bf16x8*)(wb + (((w * 4 + j) * 16 + ks) << 9) + lane * 8);
    };

    // prologue: stage half 0 of first tile
    const int t0 = blockIdx.x;
    issueLoads(t0, 0);
    convertWrite(0);

    for (int i = 0; i < 10; ++i) {
        const int t = t0 + i * GRID;

        loadB(0, 0);
        loadB(1, 1);

        // ---------- half 0: MFMA ks 0..7 on buf0; stage half 1 -> buf1 ----------
        __syncthreads();
        issueLoads(t, 1);
#pragma unroll
        for (int ksl = 0; ksl < 8; ++ksl) {
            bf16x8 af[4];
#pragma unroll
            for (int ii = 0; ii < 4; ++ii) {
                int row  = ii * 16 + lc;
                int byte = row * 512 + ksl * 64 + lkB;
                byte ^= (row & 7) << 4;
                af[ii] = *(const bf16x8*)((const char*)(&As[0][0]) + byte);
            }
            __builtin_amdgcn_s_setprio(1);
#pragma unroll
            for (int ii = 0; ii < 4; ++ii)
#pragma unroll
                for (int j = 0; j < 4; ++j)
                    acc[ii][j] = __builtin_amdgcn_mfma_f32_16x16x32_bf16(
                        af[ii], bfr[ksl & 1][j], acc[ii][j], 0, 0, 0);
            __builtin_amdgcn_s_setprio(0);
            loadB(ksl & 1, ksl + 2);          // prefetch ks+2 (2-deep)
        }
        convertWrite(1);

        // ---------- half 1: MFMA ks 8..15 on buf1; stage next tile -> buf0 ------
        __syncthreads();
        if (i < 9) issueLoads(t + GRID, 0);
#pragma unroll
        for (int ksl = 0; ksl < 8; ++ksl) {
            bf16x8 af[4];
#pragma unroll
            for (int ii = 0; ii < 4; ++ii) {
                int row  = ii * 16 + lc;
                int byte = row * 512 + ksl * 64 + lkB;
                byte ^= (row & 7) << 4;
                af[ii] = *(const bf16x8*)((const char*)(&As[1][0]) + byte);
            }
            __builtin_amdgcn_s_setprio(1);
#pragma unroll
            for (int ii = 0; ii < 4; ++ii)
#pragma unroll
                for (int j = 0; j < 4; ++j)
                    acc[ii][j] = __builtin_amdgcn_mfma_f32_16x16x32_bf16(
                        af[ii], bfr[ksl & 1][j], acc[ii][j], 0, 0, 0);
            __builtin_amdgcn_s_setprio(0);
            if (ksl < 6) loadB(ksl & 1, ksl + 10);
        }

        // epilogue: C/D layout col=lane&15, row=(lane>>4)*4+q
#pragma unroll
        for (int ii = 0; ii < 4; ++ii) {
#pragma unroll
            for (int q = 0; q < 4; ++q) {
                int row = t * BM + ii * 16 + lr + q;
                float* op = out + row * Vv + w * 64;
#pragma unroll
                for (int j = 0; j < 4; ++j)
                    op[j * 16 + lc] = acc[ii][j][q] + bia[j];
            }
        }
#pragma unroll
        for (int ii = 0; ii < 4; ++ii)
#pragma unroll
            for (int j = 0; j < 4; ++j)
                acc[ii][j] = (f32x4){0.f, 0.f, 0.f, 0.f};

        if (i < 9) convertWrite(0);
    }
}

extern "C" void kernel_launch(void* const* d_in, const int* in_sizes, int n_in,
                              void* d_out, int out_size, void* d_ws, size_t ws_size,
                              hipStream_t stream) {
    const float* enc  = (const float*)d_in[0];
    const float* pred = (const float*)d_in[1];
    const float* W    = (const float*)d_in[2];
    const float* bias = (const float*)d_in[3];
    float* out        = (float*)d_out;

    prep_kernel<<<628, 256, 0, stream>>>(W, enc, pred);
    joiner_main<<<GRID, 512, 0, stream>>>(bias, out);
}

// Round 5
// 119.671 us; speedup vs baseline: 2.2676x; 2.2676x over previous
//
#include <hip/hip_runtime.h>
#include <hip/hip_bf16.h>

typedef __attribute__((ext_vector_type(4))) float          f32x4;
typedef __attribute__((ext_vector_type(8))) short          bf16x8;
typedef __attribute__((ext_vector_type(8))) unsigned short u16x8;

#define Cc 512
#define Vv 512
#define BM 64
#define NTILE 2500

// Pre-swizzled bf16 W (MFMA B-fragment order) + f32 tanh of enc/pred rows.
__device__ unsigned short g_W2[Vv * Cc];
__device__ float g_ta[1600 * Cc];
__device__ float g_tp[400 * Cc];

__device__ __forceinline__ unsigned short f2bf(float f) {
    unsigned u = __float_as_uint(f);
    unsigned r = 0x7FFFu + ((u >> 16) & 1u);
    return (unsigned short)((u + r) >> 16);
}

__device__ __forceinline__ float fast_tanh(float x) {
    float e = __expf(2.0f * x);
    return 1.0f - 2.0f * __builtin_amdgcn_rcpf(e + 1.0f);
}

// blocks [0,128) -> W2 swizzle; [128,528) -> tanh(enc); [528,628) -> tanh(pred)
__global__ __launch_bounds__(256) void prep_kernel(
    const float* __restrict__ W, const float* __restrict__ enc,
    const float* __restrict__ pred)
{
    const int b = blockIdx.x;
    if (b < 128) {
        int gid = b * 256 + threadIdx.x;
        int v = gid >> 6;
        int k = (gid & 63) * 8;
        f32x4 a = *(const f32x4*)(W + v * Cc + k);
        f32x4 c = *(const f32x4*)(W + v * Cc + k + 4);
        u16x8 o;
#pragma unroll
        for (int j = 0; j < 4; ++j) {
            o[j]     = f2bf(a[j]);
            o[4 + j] = f2bf(c[j]);
        }
        int frag = (v >> 4) * 16 + (k >> 5);
        int lane = (v & 15) + 16 * ((k >> 3) & 3);
        *(u16x8*)(&g_W2[frag * 512 + lane * 8]) = o;
    } else if (b < 528) {
        int gid = (b - 128) * 256 + threadIdx.x;
        f32x4 a = *(const f32x4*)(enc + gid * 8);
        f32x4 c = *(const f32x4*)(enc + gid * 8 + 4);
        f32x4 o0, o1;
#pragma unroll
        for (int j = 0; j < 4; ++j) { o0[j] = fast_tanh(a[j]); o1[j] = fast_tanh(c[j]); }
        *(f32x4*)(g_ta + gid * 8)     = o0;
        *(f32x4*)(g_ta + gid * 8 + 4) = o1;
    } else {
        int gid = (b - 528) * 256 + threadIdx.x;
        f32x4 a = *(const f32x4*)(pred + gid * 8);
        f32x4 c = *(const f32x4*)(pred + gid * 8 + 4);
        f32x4 o0, o1;
#pragma unroll
        for (int j = 0; j < 4; ++j) { o0[j] = fast_tanh(a[j]); o1[j] = fast_tanh(c[j]); }
        *(f32x4*)(g_tp + gid * 8)     = o0;
        *(f32x4*)(g_tp + gid * 8 + 4) = o1;
    }
}

__global__ __launch_bounds__(512, 4) void joiner_main(
    const float* __restrict__ bias,  // (512,)
    float* __restrict__ out)         // (160000, 512)
{
    __shared__ unsigned short As[BM * Cc];   // 64 KB, XOR-swizzled rows

    const int tid = threadIdx.x;

    // ---- bijective XCD-chunked tile remap (8 XCDs, 2500 tiles) ----
    // q=312, r=4: XCDs 0-3 own 313 contiguous tiles, XCDs 4-7 own 312.
    const int xcd  = blockIdx.x & 7;
    const int idx  = blockIdx.x >> 3;
    const int tile = (xcd < 4 ? xcd * 313 : 4 * 313 + (xcd - 4) * 312) + idx;

    // ---- stage: A = tanh(enc+pred) via tanh-sum identity -> bf16 LDS ----
    {
        const int r = tid >> 3;          // 0..63 (tile row)
        const int q = tid & 7;           // k-interleave slot
        const int m  = tile * BM + r;
        const int et = m / 100;
        const int u  = m - et * 100;
        const int bb = m / 40000;
        const int pr = bb * 100 + u;
        const float* taP = g_ta + et * Cc;
        const float* tpP = g_tp + pr * Cc;
        char* asB = (char*)As;
        const int swz = (r & 7) << 4;
#pragma unroll
        for (int c = 0; c < 8; ++c) {
            const int k0 = q * 8 + c * 64;      // interleaved chunks: bank-spread
            f32x4 a0 = *(const f32x4*)(taP + k0);
            f32x4 a1 = *(const f32x4*)(taP + k0 + 4);
            f32x4 p0 = *(const f32x4*)(tpP + k0);
            f32x4 p1 = *(const f32x4*)(tpP + k0 + 4);
            u16x8 o;
#pragma unroll
            for (int j = 0; j < 4; ++j) {
                float n0 = a0[j] + p0[j];
                float d0 = __builtin_fmaf(a0[j], p0[j], 1.0f);
                o[j] = f2bf(n0 * __builtin_amdgcn_rcpf(d0));
                float n1 = a1[j] + p1[j];
                float d1 = __builtin_fmaf(a1[j], p1[j], 1.0f);
                o[4 + j] = f2bf(n1 * __builtin_amdgcn_rcpf(d1));
            }
            int byte = r * 1024 + k0 * 2;
            *(u16x8*)(asB + (byte ^ swz)) = o;
        }
    }

    // ---- compute setup; issue first B-fragments BEFORE the barrier ----
    const int lane = tid & 63;
    const int w    = tid >> 6;          // wave -> V slice [w*64, w*64+64)
    const int lc   = lane & 15;
    const int lkB  = (lane >> 4) << 4;

    const unsigned short* wb = &g_W2[0];
    bf16x8 bcur[4], bnx[4];
#pragma unroll
    for (int j = 0; j < 4; ++j)
        bcur[j] = *(const bf16x8*)(wb + (((w * 4 + j) * 16 + 0) << 9) + lane * 8);

    __syncthreads();   // only barrier

    f32x4 acc[4][4];
#pragma unroll
    for (int i = 0; i < 4; ++i)
#pragma unroll
        for (int j = 0; j < 4; ++j)
            acc[i][j] = (f32x4){0.f, 0.f, 0.f, 0.f};

    const char* asB = (const char*)As;

#pragma unroll 2
    for (int ks = 0; ks < 16; ++ks) {
        if (ks < 15) {
#pragma unroll
            for (int j = 0; j < 4; ++j)
                bnx[j] = *(const bf16x8*)(wb + (((w * 4 + j) * 16 + ks + 1) << 9) + lane * 8);
        }
        bf16x8 af[4];
#pragma unroll
        for (int i = 0; i < 4; ++i) {
            int row  = i * 16 + lc;
            int byte = row * 1024 + ks * 64 + lkB;
            byte ^= (row & 7) << 4;
            af[i] = *(const bf16x8*)(asB + byte);
        }
        __builtin_amdgcn_s_setprio(1);
#pragma unroll
        for (int i = 0; i < 4; ++i)
#pragma unroll
            for (int j = 0; j < 4; ++j)
                acc[i][j] = __builtin_amdgcn_mfma_f32_16x16x32_bf16(
                    af[i], bcur[j], acc[i][j], 0, 0, 0);
        __builtin_amdgcn_s_setprio(0);
#pragma unroll
        for (int j = 0; j < 4; ++j) bcur[j] = bnx[j];
    }

    // ---- epilogue: C/D layout col=lane&15, row=(lane>>4)*4+q; nt stores ----
    const int lr = (lane >> 4) << 2;
    float bia[4];
#pragma unroll
    for (int j = 0; j < 4; ++j) bia[j] = bias[w * 64 + j * 16 + lc];
#pragma unroll
    for (int i = 0; i < 4; ++i) {
#pragma unroll
        for (int q = 0; q < 4; ++q) {
            int row = tile * BM + i * 16 + lr + q;
            float* op = out + row * Vv + w * 64;
#pragma unroll
            for (int j = 0; j < 4; ++j)
                __builtin_nontemporal_store(acc[i][j][q] + bia[j], op + j * 16 + lc);
        }
    }
}

extern "C" void kernel_launch(void* const* d_in, const int* in_sizes, int n_in,
                              void* d_out, int out_size, void* d_ws, size_t ws_size,
                              hipStream_t stream) {
    const float* enc  = (const float*)d_in[0];
    const float* pred = (const float*)d_in[1];
    const float* W    = (const float*)d_in[2];
    const float* bias = (const float*)d_in[3];
    float* out        = (float*)d_out;

    prep_kernel<<<628, 256, 0, stream>>>(W, enc, pred);
    joiner_main<<<NTILE, 512, 0, stream>>>(bias, out);
}